// Round 9
// baseline (192.553 us; speedup 1.0000x reference)
//
#include <hip/hip_runtime.h>
#include <math.h>
#include <stdint.h>

// Problem constants (static per reference):
//   B=32, N_ATOMS=128, C=25 (rep 2,2,0), RADIUS=8, MAX_NEIGHBORS=32
#define NATOMS   128
#define NCELLS   25
#define NCAND    (NATOMS * NCELLS)   // 3200 candidates per center atom
#define MAXNB    32
#define R2       64.0f
#define BLK      256
#define KEYCAP   128

// native clang vector type for __builtin_nontemporal_store (HIP_vector_type
// float4 is a struct and is rejected by the builtin)
typedef float vfloat4 __attribute__((ext_vector_type(4)));

// d2 chain replicated exactly as the reference (no FMA contraction):
// dv = (pos_j - pos_i) + off ; d2 = (dx*dx + dy*dy) + dz*dz
__device__ __forceinline__ float d2_exact(float4 p, float4 ctr, float4 o) {
    float dx = __fadd_rn(__fsub_rn(p.x, ctr.x), o.x);
    float dy = __fadd_rn(__fsub_rn(p.y, ctr.y), o.y);
    float dz = __fadd_rn(__fsub_rn(p.z, ctr.z), o.z);
    return __fadd_rn(__fadd_rn(__fmul_rn(dx,dx), __fmul_rn(dy,dy)),
                     __fmul_rn(dz,dz));
}

// 2048 blocks (all co-resident at 8 blocks/CU, ~17.5 KB LDS); each block does
// TWO centers of one image. Selection (proven R2 path): fine histogram of d2
// in [0,16) (32nd NN at d2~2.6), wave-shuffle prefix scan, exact stable cutoff
// key (d2 bits << 32 | flat f = jnp stable argsort tie-break) among the
// critical bin's members; full-range retry + rescan fallback for robustness.
// R7/R8: outputs written with NONTEMPORAL stores — R5/R6 counters show stores
// at ~2.4 TB/s through the L2 write-allocate path while the runtime's fill
// does 6.5 TB/s; nt bypasses L2 allocation for this write-once 157 MB stream.
// NOTE: no fenced/scoped atomics — agent-scope release/acquire emits
// buffer_wbl2/buffer_inv per block (R5: 4096 L2 flushes -> 176 us kernel).
// Plain atomicAdd is device-scope by default and cheap (R3-verified).
__global__ __launch_bounds__(BLK) void graph_kernel(
    const float* __restrict__ pos, const float* __restrict__ cell,
    float* __restrict__ out_dist, float* __restrict__ out_ctype,
    float* __restrict__ out_mask, float* __restrict__ out_nb)
{
    __shared__ float4 s_pos4[NATOMS];
    __shared__ float4 s_off4[NCELLS];
    __shared__ float  s_ct[NCELLS];
    __shared__ float  s_d2[NCAND];             // inf where not within
    __shared__ unsigned s_hist[256];
    __shared__ unsigned s_wtot[4];
    __shared__ int s_wred[4];
    __shared__ unsigned long long s_keys[KEYCAP];
    __shared__ unsigned s_cnt;
    __shared__ int s_binsel, s_need, s_tot, s_att;
    __shared__ unsigned long long s_K;

    const int blk  = blockIdx.x;       // 0..2047
    const int b    = blk >> 6;         // image
    const int i0   = (blk & 63) << 1;  // first of two centers
    const int tid  = threadIdx.x;
    const int lane = tid & 63;
    const int w    = tid >> 6;

    // ---- stage image-level inputs once (disjoint thread ranges) ----
    if (tid < NATOMS) {
        const float* p = pos + (b * NATOMS + tid) * 3;
        s_pos4[tid] = make_float4(p[0], p[1], p[2], 0.0f);
    }
    if (tid >= 160 && tid < 160 + NCELLS) {
        int c = tid - 160;
        float ux = (float)(c / 5 - 2);
        float uy = (float)(c % 5 - 2);
        // off = ux*row0 + uy*row1; products exact (|u|<=2), one rounded add.
        float ox = __fadd_rn(__fmul_rn(ux, cell[b*9+0]), __fmul_rn(uy, cell[b*9+3]));
        float oy = __fadd_rn(__fmul_rn(ux, cell[b*9+1]), __fmul_rn(uy, cell[b*9+4]));
        float oz = __fadd_rn(__fmul_rn(ux, cell[b*9+2]), __fmul_rn(uy, cell[b*9+5]));
        s_off4[c] = make_float4(ox, oy, oz, 0.0f);
        // ct = (ux+2)*5 + (uy+2)*5 (mults=[5,5,1] quirk per reference)
        s_ct[c] = (float)(5 * (c / 5) + 5 * (c % 5));
    }

    #pragma unroll 1
    for (int cc = 0; cc < 2; cc++) {
        const int i  = i0 + cc;
        const int bi = (b << 7) + i;

        // barrier: (cc==0) staging done; (cc==1) epilogue-A reads of s_d2 done
        __syncthreads();
        s_hist[tid] = 0u;
        if (tid == 0) { s_cnt = 0; s_binsel = -1; s_need = 0; s_att = 0; s_K = ~0ULL; }
        __syncthreads();

        const float4 ctr = s_pos4[i];

        // ---- pass 1: d2 -> s_d2, within count, fine histogram (d2 < 16) ----
        int local = 0;
        for (int g = tid; g < NCAND; g += BLK) {
            int c = g >> 7;            // wave-uniform: s_off4 broadcast
            int j = g & 127;
            float d2 = d2_exact(s_pos4[j], ctr, s_off4[c]);
            bool within = (d2 <= R2) && (d2 > 1e-4f);
            int f = j * NCELLS + c;    // stride-25 (odd): conflict-free
            s_d2[f] = within ? d2 : __builtin_inff();
            if (within) {
                local++;
                if (d2 < 16.0f)
                    atomicAdd(&s_hist[(int)(d2 * 16.0f)], 1u);
            }
        }
        for (int o = 32; o; o >>= 1) local += __shfl_down(local, o);
        if (lane == 0) s_wred[w] = local;
        __syncthreads();
        if (tid == 0) {
            int tot = s_wred[0] + s_wred[1] + s_wred[2] + s_wred[3];
            s_tot = tot;
            // per-image clamped count; sums <=4096 -> exact in f32
            atomicAdd(&out_nb[b], (float)(tot < MAXNB ? tot : MAXNB));
        }
        __syncthreads();

        if (s_tot > MAXNB) {
            // ---- critical bin: att 0 = [0,16) fine (prebuilt); att 1 = full ----
            for (int att = 0; att < 2 && s_binsel < 0; att++) {
                if (att == 1) {   // rare path: rebuild full-range histogram
                    s_hist[tid] = 0u;
                    __syncthreads();
                    for (int v = tid; v < NCAND / 4; v += BLK) {
                        float4 dq = ((const float4*)s_d2)[v];
                        #pragma unroll
                        for (int e = 0; e < 4; e++) {
                            float d2 = (&dq.x)[e];
                            if (d2 < 64.5f) {
                                int bin = (int)(d2 * 4.0f);
                                if (bin > 255) bin = 255;
                                atomicAdd(&s_hist[bin], 1u);
                            }
                        }
                    }
                    __syncthreads();
                }
                // wave-shuffle inclusive scan of 256 bins (4 waves x 64)
                unsigned h = s_hist[tid];
                int v = (int)h;
                #pragma unroll
                for (int off = 1; off < 64; off <<= 1) {
                    int u = __shfl_up(v, off, 64);
                    if (lane >= off) v += u;
                }
                if (lane == 63) s_wtot[w] = (unsigned)v;
                __syncthreads();
                unsigned pre = 0;
                for (int ww = 0; ww < w; ww++) pre += s_wtot[ww];
                unsigned htot = s_wtot[0] + s_wtot[1] + s_wtot[2] + s_wtot[3];
                unsigned ci = (unsigned)v + pre, ce = ci - h;
                if (htot >= MAXNB && h > 0 && ce < MAXNB && ci >= MAXNB) {
                    s_binsel = tid;
                    s_need   = MAXNB - (int)ce;
                    s_att    = att;
                }
                __syncthreads();
            }

            // ---- exact cutoff key inside the critical bin ----
            const int   binsel = s_binsel;
            const float sc  = s_att ? 4.0f  : 16.0f;
            const float lim = s_att ? 64.5f : 16.0f;
            for (int v = tid; v < NCAND / 4; v += BLK) {
                float4 dq = ((const float4*)s_d2)[v];
                #pragma unroll
                for (int e = 0; e < 4; e++) {
                    float d2 = (&dq.x)[e];
                    if (d2 < lim) {
                        int bin = (int)(d2 * sc);
                        if (bin > 255) bin = 255;
                        if (bin == binsel) {
                            unsigned idx = atomicAdd(&s_cnt, 1u);
                            if (idx < KEYCAP)
                                s_keys[idx] =
                                    ((unsigned long long)__float_as_uint(d2) << 32)
                                    | (unsigned)(v * 4 + e);
                        }
                    }
                }
            }
            __syncthreads();
            const int m = (int)s_cnt, need = s_need;
            if (m <= KEYCAP) {
                for (int p = tid; p < m; p += BLK) {
                    unsigned long long kp = s_keys[p];
                    int r = 0;
                    for (int q = 0; q < m; q++) r += (s_keys[q] < kp);
                    if (r == need - 1) s_K = kp;   // keys distinct -> unique
                }
            } else {
                // never-expected overflow: rank by rescanning s_d2
                for (int f = tid; f < NCAND; f += BLK) {
                    float d2 = s_d2[f];
                    if (d2 >= lim) continue;
                    int bin = (int)(d2 * sc);
                    if (bin > 255) bin = 255;
                    if (bin != binsel) continue;
                    unsigned long long kf =
                        ((unsigned long long)__float_as_uint(d2) << 32)
                        | (unsigned)f;
                    int r = 0;
                    for (int q = 0; q < NCAND; q++) {
                        float dq = s_d2[q];
                        if (dq >= lim) continue;
                        int bq = (int)(dq * sc);
                        if (bq > 255) bq = 255;
                        if (bq != binsel) continue;
                        unsigned long long kq =
                            ((unsigned long long)__float_as_uint(dq) << 32)
                            | (unsigned)q;
                        r += (kq < kf);
                    }
                    if (r == need - 1) s_K = kf;
                }
            }
            __syncthreads();
        }
        const unsigned long long K = s_K;

        // ---- epilogue: nontemporal float4 streams (bypass L2 allocation) ----
        const long long base = (long long)bi * NCAND;
        vfloat4* o0 = (vfloat4*)(out_dist  + base);
        vfloat4* o1 = (vfloat4*)(out_ctype + base);
        vfloat4* o2 = (vfloat4*)(out_mask  + base);
        for (int v = tid; v < NCAND / 4; v += BLK) {
            float4 dq = ((const float4*)s_d2)[v];
            int f0 = v * 4;
            int c = f0 % NCELLS;       // one magic-div per 4 candidates
            vfloat4 r0, r1, r2;
            #pragma unroll
            for (int e = 0; e < 4; e++) {
                float d2 = (&dq.x)[e];
                bool within = (d2 <= R2);   // inf for non-within reconstructs mask
                unsigned long long key =
                    ((unsigned long long)__float_as_uint(d2) << 32)
                    | (unsigned)(f0 + e);
                bool keep = within && (key <= K);
                r0[e] = keep ? sqrtf(d2) : 0.0f;
                r1[e] = keep ? s_ct[c] : 0.0f;
                r2[e] = keep ? 1.0f : 0.0f;
                c++; if (c == NCELLS) c = 0;
            }
            __builtin_nontemporal_store(r0, &o0[v]);
            __builtin_nontemporal_store(r1, &o1[v]);
            __builtin_nontemporal_store(r2, &o2[v]);
        }
    }
}

extern "C" void kernel_launch(void* const* d_in, const int* in_sizes, int n_in,
                              void* d_out, int out_size, void* d_ws, size_t ws_size,
                              hipStream_t stream) {
    const float* pos  = (const float*)d_in[0];   // [32,128,3]
    const float* cell = (const float*)d_in[1];   // [32,3,3]
    float* out = (float*)d_out;
    const long long E = 32LL * NATOMS * NATOMS * NCELLS;   // 13,107,200
    float* out_dist  = out;
    float* out_ct    = out + E;
    float* out_mask  = out + 2 * E;
    float* out_nb    = out + 3 * E;                         // 32 floats

    // zero the 32 per-image counters (d_out poisoned 0xAA); 128 B memset
    (void)hipMemsetAsync(out_nb, 0, 32 * sizeof(float), stream);
    hipLaunchKernelGGL(graph_kernel, dim3(32 * NATOMS / 2), dim3(BLK), 0, stream,
                       pos, cell, out_dist, out_ct, out_mask, out_nb);
}

// Round 10
// 165.006 us; speedup vs baseline: 1.1669x; 1.1669x over previous
//
#include <hip/hip_runtime.h>
#include <math.h>
#include <stdint.h>

// Problem constants (static per reference):
//   B=32, N_ATOMS=128, C=25 (rep 2,2,0), RADIUS=8, MAX_NEIGHBORS=32
#define NATOMS   128
#define NCELLS   25
#define NCAND    (NATOMS * NCELLS)   // 3200 candidates per center atom
#define MAXNB    32
#define R2       64.0f
#define BLK      256
#define KEYCAP   192
#define DCUT     6.25f               // ballot-collect radius^2 (r=2.5A). Even for
                                     // z-boundary centers (no z-PBC -> half-space)
                                     // expected count ~65 >> 32; interior ~131.

// d2 chain replicated exactly as the reference (no FMA contraction):
// dv = (pos_j - pos_i) + off ; d2 = (dx*dx + dy*dy) + dz*dz
__device__ __forceinline__ float d2_exact(float4 p, float4 ctr, float4 o) {
    float dx = __fadd_rn(__fsub_rn(p.x, ctr.x), o.x);
    float dy = __fadd_rn(__fsub_rn(p.y, ctr.y), o.y);
    float dz = __fadd_rn(__fsub_rn(p.z, ctr.z), o.z);
    return __fadd_rn(__fadd_rn(__fmul_rn(dx,dx), __fmul_rn(dy,dy)),
                     __fmul_rn(dz,dz));
}

// 4096 blocks, one center each (~17.5 KB LDS -> 8 blocks/CU, full occupancy).
// R9: selection fast path = ballot-collect keys with d2<DCUT during pass 1
// (no LDS-atomic histogram, no prefix scan, no extra NCAND pass), then one
// m^2 rank over ~131 keys -> exact stable cutoff key (d2 bits << 32 | flat f,
// = jnp stable argsort tie-break; rank 31 = 32nd NN). Histogram path kept only
// as fallback (m<32 or m>KEYCAP; z-slab geometry makes this ~never at DCUT).
// NOTE (R5/R8 lessons): no fenced/scoped atomics (agent-scope release emits
// per-block buffer_wbl2/inv -> +110 us); no hipMemsetAsync in the launch
// (extra graph node costs ~20+ us replay latency) -> reduce_counts kernel.
__global__ __launch_bounds__(BLK) void graph_kernel(
    const float* __restrict__ pos, const float* __restrict__ cell,
    float* __restrict__ out_dist, float* __restrict__ out_ctype,
    float* __restrict__ out_mask, float* __restrict__ ws_counts)
{
    __shared__ float4 s_pos4[NATOMS];
    __shared__ float4 s_off4[NCELLS];
    __shared__ float  s_ct[NCELLS];
    __shared__ float  s_d2[NCAND];             // inf where not within
    __shared__ unsigned long long s_keys[KEYCAP];
    __shared__ unsigned s_hist[256];           // fallback only
    __shared__ unsigned s_wtot[4];
    __shared__ int s_wred[4];
    __shared__ unsigned s_cnt, s_cnt2;
    __shared__ int s_tot, s_binsel, s_need;
    __shared__ unsigned long long s_K;

    const int bi   = blockIdx.x;       // b*128 + i
    const int b    = bi >> 7;
    const int i    = bi & 127;
    const int tid  = threadIdx.x;
    const int lane = tid & 63;
    const int w    = tid >> 6;

    // ---- stage inputs into LDS (disjoint thread ranges) ----
    if (tid < NATOMS) {
        const float* p = pos + (b * NATOMS + tid) * 3;
        s_pos4[tid] = make_float4(p[0], p[1], p[2], 0.0f);
    }
    if (tid >= 160 && tid < 160 + NCELLS) {
        int c = tid - 160;
        float ux = (float)(c / 5 - 2);
        float uy = (float)(c % 5 - 2);
        // off = ux*row0 + uy*row1; products exact (|u|<=2), one rounded add.
        float ox = __fadd_rn(__fmul_rn(ux, cell[b*9+0]), __fmul_rn(uy, cell[b*9+3]));
        float oy = __fadd_rn(__fmul_rn(ux, cell[b*9+1]), __fmul_rn(uy, cell[b*9+4]));
        float oz = __fadd_rn(__fmul_rn(ux, cell[b*9+2]), __fmul_rn(uy, cell[b*9+5]));
        s_off4[c] = make_float4(ox, oy, oz, 0.0f);
        // ct = (ux+2)*5 + (uy+2)*5 (mults=[5,5,1] quirk per reference)
        s_ct[c] = (float)(5 * (c / 5) + 5 * (c % 5));
    }
    if (tid == 0) { s_cnt = 0; s_cnt2 = 0; s_binsel = -1; s_need = 0; s_K = ~0ULL; }
    __syncthreads();

    const float4 ctr = s_pos4[i];

    // ---- pass 1: d2 -> s_d2, within count, ballot-collect keys (d2 < DCUT) ----
    int local = 0;
    for (int g = tid; g < NCAND; g += BLK) {
        int c = g >> 7;            // wave-uniform: s_off4 broadcast
        int j = g & 127;
        float d2 = d2_exact(s_pos4[j], ctr, s_off4[c]);
        bool within = (d2 <= R2) && (d2 > 1e-4f);
        int f = j * NCELLS + c;    // stride-25 (odd): conflict-free
        s_d2[f] = within ? d2 : __builtin_inff();
        local += within;
        bool sel = within && (d2 < DCUT);
        unsigned long long mb = __ballot(sel);
        if (mb) {                  // ~2-3 of 12.5 iterations have any hit
            unsigned cnt = (unsigned)__popcll(mb);
            unsigned base = 0;
            if (lane == 0) base = atomicAdd(&s_cnt, cnt);
            base = __shfl(base, 0);
            if (sel) {
                unsigned p = base + (unsigned)__popcll(mb & ((1ULL << lane) - 1ULL));
                if (p < KEYCAP)
                    s_keys[p] = ((unsigned long long)__float_as_uint(d2) << 32)
                                | (unsigned)f;
            }
        }
    }
    for (int o = 32; o; o >>= 1) local += __shfl_down(local, o);
    if (lane == 0) s_wred[w] = local;
    __syncthreads();
    if (tid == 0) {
        int tot = s_wred[0] + s_wred[1] + s_wred[2] + s_wred[3];
        s_tot = tot;
        ws_counts[bi] = (float)(tot < MAXNB ? tot : MAXNB);
    }
    __syncthreads();

    if (s_tot > MAXNB) {
        const unsigned m = s_cnt;
        if (m >= MAXNB && m <= KEYCAP) {
            // ---- fast path: rank the ~131 collected keys; rank 31 = cutoff ----
            for (unsigned p = tid; p < m; p += BLK) {
                unsigned long long kp = s_keys[p];
                int r = 0;
                for (unsigned q = 0; q < m; q++) r += (s_keys[q] < kp);
                if (r == MAXNB - 1) s_K = kp;   // keys distinct -> unique
            }
        } else {
            // ---- fallback (never expected): histogram over s_d2 ----
            s_hist[tid] = 0u;
            __syncthreads();
            for (int v = tid; v < NCAND / 4; v += BLK) {
                float4 dq = ((const float4*)s_d2)[v];
                #pragma unroll
                for (int e = 0; e < 4; e++) {
                    float d2 = (&dq.x)[e];
                    if (d2 < 64.5f) {
                        int bin = (int)(d2 * 4.0f);
                        if (bin > 255) bin = 255;
                        atomicAdd(&s_hist[bin], 1u);
                    }
                }
            }
            __syncthreads();
            unsigned h = s_hist[tid];
            int v = (int)h;
            #pragma unroll
            for (int off = 1; off < 64; off <<= 1) {
                int u = __shfl_up(v, off, 64);
                if (lane >= off) v += u;
            }
            if (lane == 63) s_wtot[w] = (unsigned)v;
            __syncthreads();
            unsigned pre = 0;
            for (int ww = 0; ww < w; ww++) pre += s_wtot[ww];
            unsigned ci = (unsigned)v + pre, ce = ci - h;
            if (h > 0 && ce < MAXNB && ci >= MAXNB) {
                s_binsel = tid;
                s_need   = MAXNB - (int)ce;
            }
            __syncthreads();
            const int binsel = s_binsel, need = s_need;
            for (int f = tid; f < NCAND; f += BLK) {
                float d2 = s_d2[f];
                if (d2 < 64.5f) {
                    int bin = (int)(d2 * 4.0f);
                    if (bin > 255) bin = 255;
                    if (bin == binsel) {
                        unsigned idx = atomicAdd(&s_cnt2, 1u);
                        if (idx < KEYCAP)
                            s_keys[idx] =
                                ((unsigned long long)__float_as_uint(d2) << 32)
                                | (unsigned)f;
                    }
                }
            }
            __syncthreads();
            const int m2 = (int)s_cnt2;
            if (m2 <= KEYCAP) {
                for (int p = tid; p < m2; p += BLK) {
                    unsigned long long kp = s_keys[p];
                    int r = 0;
                    for (int q = 0; q < m2; q++) r += (s_keys[q] < kp);
                    if (r == need - 1) s_K = kp;
                }
            } else {
                // critical-bin overflow: rank by rescanning s_d2
                for (int f = tid; f < NCAND; f += BLK) {
                    float d2 = s_d2[f];
                    if (d2 >= 64.5f) continue;
                    int bin = (int)(d2 * 4.0f);
                    if (bin > 255) bin = 255;
                    if (bin != binsel) continue;
                    unsigned long long kf =
                        ((unsigned long long)__float_as_uint(d2) << 32)
                        | (unsigned)f;
                    int r = 0;
                    for (int q = 0; q < NCAND; q++) {
                        float dq = s_d2[q];
                        if (dq >= 64.5f) continue;
                        int bq = (int)(dq * 4.0f);
                        if (bq > 255) bq = 255;
                        if (bq != binsel) continue;
                        unsigned long long kq =
                            ((unsigned long long)__float_as_uint(dq) << 32)
                            | (unsigned)q;
                        r += (kq < kf);
                    }
                    if (r == need - 1) s_K = kf;
                }
            }
        }
    }
    __syncthreads();
    const unsigned long long K = s_K;

    // ---- epilogue: stream outputs from s_d2 (float4, coalesced) ----
    const long long base = (long long)bi * NCAND;
    float4* o0 = (float4*)(out_dist  + base);
    float4* o1 = (float4*)(out_ctype + base);
    float4* o2 = (float4*)(out_mask  + base);
    for (int v = tid; v < NCAND / 4; v += BLK) {
        float4 dq = ((const float4*)s_d2)[v];
        int f0 = v * 4;
        int c = f0 % NCELLS;       // one magic-div per 4 candidates
        float4 r0, r1, r2;
        #pragma unroll
        for (int e = 0; e < 4; e++) {
            float d2 = (&dq.x)[e];
            bool within = (d2 <= R2);   // inf for non-within reconstructs mask
            unsigned long long key =
                ((unsigned long long)__float_as_uint(d2) << 32)
                | (unsigned)(f0 + e);
            bool keep = within && (key <= K);
            (&r0.x)[e] = keep ? sqrtf(d2) : 0.0f;
            (&r1.x)[e] = keep ? s_ct[c] : 0.0f;
            (&r2.x)[e] = keep ? 1.0f : 0.0f;
            c++; if (c == NCELLS) c = 0;
        }
        o0[v] = r0; o1[v] = r1; o2[v] = r2;
    }
}

// Reduce per-center clamped counts -> per-image totals (exact in f32).
__global__ __launch_bounds__(64) void reduce_counts(
    const float* __restrict__ ws_counts, float* __restrict__ out_nb)
{
    int b = blockIdx.x;
    int t = threadIdx.x;    // 64 threads
    float v = ws_counts[b * NATOMS + t] + ws_counts[b * NATOMS + 64 + t];
    for (int o = 32; o; o >>= 1) v += __shfl_down(v, o);
    if (t == 0) out_nb[b] = v;
}

extern "C" void kernel_launch(void* const* d_in, const int* in_sizes, int n_in,
                              void* d_out, int out_size, void* d_ws, size_t ws_size,
                              hipStream_t stream) {
    const float* pos  = (const float*)d_in[0];   // [32,128,3]
    const float* cell = (const float*)d_in[1];   // [32,3,3]
    float* out = (float*)d_out;
    const long long E = 32LL * NATOMS * NATOMS * NCELLS;   // 13,107,200
    float* out_dist  = out;
    float* out_ct    = out + E;
    float* out_mask  = out + 2 * E;
    float* out_nb    = out + 3 * E;                         // 32 floats
    float* ws = (float*)d_ws;                               // 4096 floats

    hipLaunchKernelGGL(graph_kernel, dim3(32 * NATOMS), dim3(BLK), 0, stream,
                       pos, cell, out_dist, out_ct, out_mask, ws);
    hipLaunchKernelGGL(reduce_counts, dim3(32), dim3(64), 0, stream,
                       ws, out_nb);
}